// Round 6
// baseline (187.651 us; speedup 1.0000x reference)
//
#include <hip/hip_runtime.h>

typedef unsigned char u8;
typedef unsigned short u16;
typedef float f32x4 __attribute__((ext_vector_type(4)));
typedef int i32x4 __attribute__((ext_vector_type(4)));
typedef int i32x8 __attribute__((ext_vector_type(8)));

#define NROWS 16384
#define DIM 128

// exp(-2*sim) = exp2(sim * -2*log2(e)); scale folded into normalized B rows.
#define NEG2LOG2E -2.8853900817779268f
#define SCALE ((float)(1.0 / (16384.0 * 16383.0)))

// E8M0 scale byte 127 = 2^0 = 1.0, replicated.
#define SCALE1 0x7F7F7F7F

#define KMAX 320
#define NCORR 100
#define NGEMM 4096

// Two rows per wave (half-wave per row): float4 loads, half-wave shuffle
// reduction, paired cvt_pk_fp8 -> one dword store per lane (fully coalesced).
// B rows pre-scaled by -2*log2(e) so GEMM output feeds exp2 directly.
// Block 0 / tid 0 zeroes the finalize ticket counter (stream-ordered before
// gemm, so the counter is always 0 when gemm starts).
__global__ __launch_bounds__(256) void norm_kernel(
    const float* __restrict__ a, const float* __restrict__ b,
    u8* __restrict__ aO, u8* __restrict__ bO, int* __restrict__ cnt)
{
    if (blockIdx.x == 0 && threadIdx.x == 0) *cnt = 0;

    int tid  = threadIdx.x;
    int lane = tid & 63;
    int w    = tid >> 6;
    int half = lane >> 5;
    int l32  = lane & 31;
    long row = (long)blockIdx.x * 8 + w * 2 + half;

    const float4 va = ((const float4*)(a + row * DIM))[l32];
    float sa = va.x * va.x + va.y * va.y + va.z * va.z + va.w * va.w;
    #pragma unroll
    for (int off = 16; off; off >>= 1) sa += __shfl_xor(sa, off, 64);
    float inva = 1.0f / fmaxf(sqrtf(sa), 1e-12f);
    int pa = __builtin_amdgcn_cvt_pk_fp8_f32(va.x * inva, va.y * inva, 0, false);
    pa = __builtin_amdgcn_cvt_pk_fp8_f32(va.z * inva, va.w * inva, pa, true);
    ((int*)(aO + row * DIM))[l32] = pa;

    const float4 vb = ((const float4*)(b + row * DIM))[l32];
    float sb = vb.x * vb.x + vb.y * vb.y + vb.z * vb.z + vb.w * vb.w;
    #pragma unroll
    for (int off = 16; off; off >>= 1) sb += __shfl_xor(sb, off, 64);
    float invb = NEG2LOG2E / fmaxf(sqrtf(sb), 1e-12f);
    int pb = __builtin_amdgcn_cvt_pk_fp8_f32(vb.x * invb, vb.y * invb, 0, false);
    pb = __builtin_amdgcn_cvt_pk_fp8_f32(vb.z * invb, vb.w * invb, pb, true);
    ((int*)(bO + row * DIM))[l32] = pb;
}

// 1D grid of 100 + 4096 blocks. IDs 0..99: correction block for label id —
// dispatched FIRST so their latency chains hide under the gemm fill phase.
// IDs 100+: maskless 128x512 GEMM strip (R10 structure, proven 51.8us);
// same-label sums subtracted exactly in the fused finalize.
//
// R16: reverted to the exact R10 cooperative-staging structure (every
// restructure R11-R15 regressed with identical profiles -> the stall is
// structure-invariant; R10's per-block B staging minimizes staging traffic).
// Two orthogonal micro-fixes kept: constant-zero C operand (no per-jt acc
// re-init movs) and 4 independent epilogue sum chains. NEW: the final
// reduction is fused via device-scope ticket -- the last block to finish
// sums the 4096 partials - 100 corrections and writes out[0], removing the
// third kernel launch (+its inter-kernel gap) entirely.
__global__ __launch_bounds__(256, 3) void gemm_kernel(
    const u8* __restrict__ A, const u8* __restrict__ B,
    const int* __restrict__ labels,
    float* __restrict__ partials, float* __restrict__ corrP,
    float* __restrict__ out, int* __restrict__ cnt)
{
    __shared__ u8 sA[16384];
    __shared__ u8 sB[2][16384];
    __shared__ float fRed[4];
    __shared__ int lastFlag;

    int tid  = threadIdx.x;
    int lane = tid & 63;
    int w    = tid >> 6;
    int mrow = lane & 15;
    int q    = lane >> 4;

// Last-finisher fused reduction: release-fence + ticket; the block that
// draws the final ticket acquires and reduces all partials/corrections.
// Graceful under rocprof standalone-replay with a stale counter: no block
// becomes last -> out simply isn't rewritten (no spin, no deadlock).
#define FINALIZE() do {                                                       \
        if (tid == 0) {                                                       \
            __threadfence();                                                  \
            int t_ = atomicAdd(cnt, 1);                                       \
            lastFlag = (t_ == NCORR + NGEMM - 1);                             \
        }                                                                     \
        __syncthreads();                                                      \
        if (lastFlag) {                                                       \
            __threadfence();                                                  \
            const float4* p4_ = (const float4*)partials;                      \
            float fs_ = 0.0f;                                                 \
            _Pragma("unroll 4")                                               \
            for (int i_ = tid; i_ < NGEMM / 4; i_ += 256) {                   \
                float4 v_ = p4_[i_];                                          \
                fs_ += (v_.x + v_.y) + (v_.z + v_.w);                         \
            }                                                                 \
            if (tid < NCORR) fs_ -= corrP[tid];                               \
            _Pragma("unroll")                                                 \
            for (int off_ = 32; off_; off_ >>= 1)                             \
                fs_ += __shfl_xor(fs_, off_, 64);                             \
            if (lane == 0) fRed[w] = fs_;                                     \
            __syncthreads();                                                  \
            if (tid == 0)                                                     \
                out[0] = (fRed[0] + fRed[1]) + (fRed[2] + fRed[3]);           \
        } } while (0)

    if (blockIdx.x < NCORR) {
        // ---------------- correction path (early blocks) ----------------
        int l = blockIdx.x;
        int* sIdx = (int*)sA;                 // KMAX ints
        __shared__ int sCnt;
        if (tid == 0) sCnt = 0;
        __syncthreads();

        for (int i = tid; i < NROWS; i += 256)
            if (labels[i] == l) {
                int p = atomicAdd(&sCnt, 1);
                if (p < KMAX) sIdx[p] = i;
            }
        __syncthreads();

        int k = sCnt < KMAX ? sCnt : KMAX;
        int nt = (k + 15) >> 4;
        int ntk = nt << 4;
        for (int r = k + tid; r < ntk; r += 256) sIdx[r] = sIdx[0];  // pad
        __syncthreads();

        int npairs = nt * nt;
        float s = 0.0f;
        // 2-deep software pipeline: two tile-pairs per iteration, gathers
        // issued together so their L2 latency overlaps.
        for (int tp = w; tp < npairs; tp += 8) {
            int tpB = tp + 4;
            bool has2 = tpB < npairs;
            int tp2 = has2 ? tpB : tp;

            int ti1 = tp / nt,  tj1 = tp  - ti1 * nt;
            int ti2 = tp2 / nt, tj2 = tp2 - ti2 * nt;
            int ri1 = sIdx[ti1 * 16 + mrow], rj1 = sIdx[tj1 * 16 + mrow];
            int ri2 = sIdx[ti2 * 16 + mrow], rj2 = sIdx[tj2 * 16 + mrow];

            const u8* pa1 = A + (size_t)ri1 * DIM + q * 32;
            const u8* pb1 = B + (size_t)rj1 * DIM + q * 32;
            const u8* pa2 = A + (size_t)ri2 * DIM + q * 32;
            const u8* pb2 = B + (size_t)rj2 * DIM + q * 32;

            i32x8 aF1, bF1, aF2, bF2;
            *((i32x4*)&aF1)     = *(const i32x4*)pa1;
            *((i32x4*)&aF1 + 1) = *(const i32x4*)(pa1 + 16);
            *((i32x4*)&bF1)     = *(const i32x4*)pb1;
            *((i32x4*)&bF1 + 1) = *(const i32x4*)(pb1 + 16);
            *((i32x4*)&aF2)     = *(const i32x4*)pa2;
            *((i32x4*)&aF2 + 1) = *(const i32x4*)(pa2 + 16);
            *((i32x4*)&bF2)     = *(const i32x4*)pb2;
            *((i32x4*)&bF2 + 1) = *(const i32x4*)(pb2 + 16);

            f32x4 acc1 = (f32x4){0.f, 0.f, 0.f, 0.f};
            f32x4 acc2 = (f32x4){0.f, 0.f, 0.f, 0.f};
            acc1 = __builtin_amdgcn_mfma_scale_f32_16x16x128_f8f6f4(
                aF1, bF1, acc1, 0, 0, 0, SCALE1, 0, SCALE1);
            acc2 = __builtin_amdgcn_mfma_scale_f32_16x16x128_f8f6f4(
                aF2, bF2, acc2, 0, 0, 0, SCALE1, 0, SCALE1);

            int i1 = ti1 * 16 + q * 4, j1 = tj1 * 16 + mrow;
            int i2 = ti2 * 16 + q * 4, j2 = tj2 * 16 + mrow;
            #pragma unroll
            for (int r = 0; r < 4; r++) {
                float e1 = __builtin_amdgcn_exp2f(acc1[r]);
                s += ((i1 + r) < k && j1 < k) ? e1 : 0.0f;
                float e2 = __builtin_amdgcn_exp2f(acc2[r]);
                s += (has2 && (i2 + r) < k && j2 < k) ? e2 : 0.0f;
            }
        }

        #pragma unroll
        for (int off = 32; off; off >>= 1) s += __shfl_xor(s, off, 64);
        if (lane == 0) fRed[w] = s;
        __syncthreads();
        if (tid == 0)
            corrP[l] = (fRed[0] + fRed[1] + fRed[2] + fRed[3]) * SCALE;

        FINALIZE();
        return;
    }

    // ---------------- maskless GEMM path ----------------
    int g  = blockIdx.x - NCORR;
    int wr = w >> 1;
    int wc = w & 1;

    int rowBase = (g >> 5) * 128;
    int colBase = (g & 31) * 512;

    // Staging pattern: LDS granule g of row m holds global granule g^(m&7).
    int m0 = tid >> 3;
    int p0 = tid & 7;
    int srcOff = m0 * 128 + ((p0 ^ (m0 & 7)) << 4);
    int ldsOff = (tid - lane) * 16;      // wave-uniform base

    const u8* gA = A + (size_t)rowBase * DIM + srcOff;
    const u8* gB = B + (size_t)colBase * DIM + srcOff;

    {
        const u8* gpA = gA;
        const u8* gpB = gB;
        u8* lpA = &sA[ldsOff];
        u8* lpB = &sB[0][ldsOff];
        #pragma unroll
        for (int it = 0; it < 4; it++) {
            __builtin_amdgcn_global_load_lds(
                (const __attribute__((address_space(1))) void*)gpA,
                (__attribute__((address_space(3))) void*)lpA, 16, 0, 0);
            __builtin_amdgcn_global_load_lds(
                (const __attribute__((address_space(1))) void*)gpB,
                (__attribute__((address_space(3))) void*)lpB, 16, 0, 0);
            gpA += 4096; gpB += 4096; lpA += 4096; lpB += 4096;
        }
    }

    // Fragment LDS byte offsets: low granule (2q)^(row&7); high = ^16.
    int aOff[4], bOff[4];
    #pragma unroll
    for (int mi = 0; mi < 4; mi++) {
        int m = wr * 64 + mi * 16 + mrow;
        aOff[mi] = m * 128 + (((q << 1) ^ (m & 7)) << 4);
        int n = wc * 64 + mi * 16 + mrow;
        bOff[mi] = n * 128 + (((q << 1) ^ (n & 7)) << 4);
    }

    __syncthreads();   // A + B0 resident

    // A operands register-resident for all 4 tiles (32 VGPRs).
    i32x8 a8[4];
    #pragma unroll
    for (int mi = 0; mi < 4; mi++) {
        *((i32x4*)&a8[mi])     = *(const i32x4*)(sA + aOff[mi]);
        *((i32x4*)&a8[mi] + 1) = *(const i32x4*)(sA + (aOff[mi] ^ 16));
    }

    const f32x4 z4 = (f32x4){0.f, 0.f, 0.f, 0.f};
    float s0 = 0.0f, s1 = 0.0f, s2 = 0.0f, s3 = 0.0f;

    #pragma unroll
    for (int jt = 0; jt < 4; jt++) {
        if (jt < 3) {
            const u8* gp = gB + (jt + 1) * (128 * DIM);
            u8* lp = &sB[(jt + 1) & 1][ldsOff];
            #pragma unroll
            for (int it = 0; it < 4; it++) {
                __builtin_amdgcn_global_load_lds(
                    (const __attribute__((address_space(1))) void*)gp,
                    (__attribute__((address_space(3))) void*)lp, 16, 0, 0);
                gp += 4096; lp += 4096;
            }
        }

        const u8* sb = sB[jt & 1];
        i32x8 b8[4];
        #pragma unroll
        for (int ni = 0; ni < 4; ni++) {
            *((i32x4*)&b8[ni])     = *(const i32x4*)(sb + bOff[ni]);
            *((i32x4*)&b8[ni] + 1) = *(const i32x4*)(sb + (bOff[ni] ^ 16));
        }

        // C operand constant-zero: no per-tile acc re-init movs.
        f32x4 acc[4][4];
        #pragma unroll
        for (int mi = 0; mi < 4; mi++)
            #pragma unroll
            for (int ni = 0; ni < 4; ni++)
                acc[mi][ni] = __builtin_amdgcn_mfma_scale_f32_16x16x128_f8f6f4(
                    a8[mi], b8[ni], z4, 0, 0, 0, SCALE1, 0, SCALE1);

        // Maskless epilogue: exp2 + add only, 4 independent chains.
        #pragma unroll
        for (int mi = 0; mi < 4; mi++)
            #pragma unroll
            for (int ni = 0; ni < 4; ni++) {
                s0 += __builtin_amdgcn_exp2f(acc[mi][ni][0]);
                s1 += __builtin_amdgcn_exp2f(acc[mi][ni][1]);
                s2 += __builtin_amdgcn_exp2f(acc[mi][ni][2]);
                s3 += __builtin_amdgcn_exp2f(acc[mi][ni][3]);
            }

        __syncthreads();
    }

    float s = (s0 + s1) + (s2 + s3);
    #pragma unroll
    for (int off = 32; off; off >>= 1) s += __shfl_xor(s, off, 64);

    if (lane == 0) fRed[w] = s;
    __syncthreads();
    if (tid == 0) {
        float t = (fRed[0] + fRed[1]) + (fRed[2] + fRed[3]);
        partials[g] = t * SCALE;
    }

    FINALIZE();
#undef FINALIZE
}

extern "C" void kernel_launch(void* const* d_in, const int* in_sizes, int n_in,
                              void* d_out, int out_size, void* d_ws, size_t ws_size,
                              hipStream_t stream) {
    const float* self_p = (const float*)d_in[0];
    const float* pos_p  = (const float*)d_in[1];
    const int*   labels = (const int*)d_in[2];
    float* out = (float*)d_out;

    u8* aB = (u8*)d_ws;                         // 2 MB fp8 normalized self
    u8* bB = aB + (size_t)NROWS * DIM;          // 2 MB fp8 normalized pos (pre-scaled)
    float* gemmP = (float*)(bB + (size_t)NROWS * DIM);     // 16 KB
    float* corrP = gemmP + NGEMM;                           // 512 B slot (100 used)
    int*   cnt   = (int*)(corrP + 128);                     // finalize ticket

    norm_kernel<<<NROWS / 8, 256, 0, stream>>>(self_p, pos_p, aB, bB, cnt);
    gemm_kernel<<<NCORR + NGEMM, 256, 0, stream>>>(aB, bB, labels, gemmP, corrP,
                                                   out, cnt);
}

// Round 7
// 127.337 us; speedup vs baseline: 1.4737x; 1.4737x over previous
//
#include <hip/hip_runtime.h>

typedef unsigned char u8;
typedef unsigned short u16;
typedef float f32x4 __attribute__((ext_vector_type(4)));
typedef int i32x4 __attribute__((ext_vector_type(4)));
typedef int i32x8 __attribute__((ext_vector_type(8)));

#define NROWS 16384
#define DIM 128

// exp(-2*sim) = exp2(sim * -2*log2(e)); scale folded into normalized B rows.
#define NEG2LOG2E -2.8853900817779268f
#define SCALE ((float)(1.0 / (16384.0 * 16383.0)))

// E8M0 scale byte 127 = 2^0 = 1.0, replicated.
#define SCALE1 0x7F7F7F7F

#define KMAX 320
#define NCORR 100
#define NGEMM 4096

// Two rows per wave (half-wave per row): float4 loads, half-wave shuffle
// reduction, paired cvt_pk_fp8 -> one dword store per lane (fully coalesced).
// B rows pre-scaled by -2*log2(e) so GEMM output feeds exp2 directly.
// Block 0 zeroes out[0] (stream-ordered before gemm's atomic accumulate).
__global__ __launch_bounds__(256) void norm_kernel(
    const float* __restrict__ a, const float* __restrict__ b,
    u8* __restrict__ aO, u8* __restrict__ bO, float* __restrict__ out)
{
    if (blockIdx.x == 0 && threadIdx.x == 0) out[0] = 0.0f;

    int tid  = threadIdx.x;
    int lane = tid & 63;
    int w    = tid >> 6;
    int half = lane >> 5;
    int l32  = lane & 31;
    long row = (long)blockIdx.x * 8 + w * 2 + half;

    const float4 va = ((const float4*)(a + row * DIM))[l32];
    float sa = va.x * va.x + va.y * va.y + va.z * va.z + va.w * va.w;
    #pragma unroll
    for (int off = 16; off; off >>= 1) sa += __shfl_xor(sa, off, 64);
    float inva = 1.0f / fmaxf(sqrtf(sa), 1e-12f);
    int pa = __builtin_amdgcn_cvt_pk_fp8_f32(va.x * inva, va.y * inva, 0, false);
    pa = __builtin_amdgcn_cvt_pk_fp8_f32(va.z * inva, va.w * inva, pa, true);
    ((int*)(aO + row * DIM))[l32] = pa;

    const float4 vb = ((const float4*)(b + row * DIM))[l32];
    float sb = vb.x * vb.x + vb.y * vb.y + vb.z * vb.z + vb.w * vb.w;
    #pragma unroll
    for (int off = 16; off; off >>= 1) sb += __shfl_xor(sb, off, 64);
    float invb = NEG2LOG2E / fmaxf(sqrtf(sb), 1e-12f);
    int pb = __builtin_amdgcn_cvt_pk_fp8_f32(vb.x * invb, vb.y * invb, 0, false);
    pb = __builtin_amdgcn_cvt_pk_fp8_f32(vb.z * invb, vb.w * invb, pb, true);
    ((int*)(bO + row * DIM))[l32] = pb;
}

// 1D grid of 100 + 4096 blocks. IDs 0..99: correction block for label id —
// dispatched FIRST so their latency chains hide under the gemm fill phase.
// IDs 100+: maskless 128x512 GEMM strip (sums exp over ALL pairs);
// same-label sums subtracted exactly via the correction blocks.
//
// R17: exact R0 structure (best measured: gemm 51.8us; every restructure
// R11-R15 regressed). Final reduction fused WITHOUT fences: each block
// contributes one device-scope atomicAdd(float) to out[0] (gemm: +s*SCALE,
// correction: -corr). Atomic RMWs resolve at the coherent point -- no
// __threadfence (R16's per-block agent-scope fence forced L2 writebacks
// and blew gemm up to 126us on non-coherent-L2 XCDs). No partials array,
// no reduce kernel, one launch removed.
__global__ __launch_bounds__(256, 3) void gemm_kernel(
    const u8* __restrict__ A, const u8* __restrict__ B,
    const int* __restrict__ labels,
    float* __restrict__ out)
{
    __shared__ u8 sA[16384];
    __shared__ u8 sB[2][16384];

    int tid  = threadIdx.x;
    int lane = tid & 63;
    int w    = tid >> 6;
    int mrow = lane & 15;
    int q    = lane >> 4;

    if (blockIdx.x < NCORR) {
        // ---------------- correction path (early blocks) ----------------
        int l = blockIdx.x;
        int* sIdx = (int*)sA;                 // KMAX ints
        __shared__ int sCnt;
        __shared__ float red[4];
        if (tid == 0) sCnt = 0;
        __syncthreads();

        for (int i = tid; i < NROWS; i += 256)
            if (labels[i] == l) {
                int p = atomicAdd(&sCnt, 1);
                if (p < KMAX) sIdx[p] = i;
            }
        __syncthreads();

        int k = sCnt < KMAX ? sCnt : KMAX;
        int nt = (k + 15) >> 4;
        int ntk = nt << 4;
        for (int r = k + tid; r < ntk; r += 256) sIdx[r] = sIdx[0];  // pad
        __syncthreads();

        int npairs = nt * nt;
        float s = 0.0f;
        // 2-deep software pipeline: two tile-pairs per iteration, gathers
        // issued together so their L2 latency overlaps.
        for (int tp = w; tp < npairs; tp += 8) {
            int tpB = tp + 4;
            bool has2 = tpB < npairs;
            int tp2 = has2 ? tpB : tp;

            int ti1 = tp / nt,  tj1 = tp  - ti1 * nt;
            int ti2 = tp2 / nt, tj2 = tp2 - ti2 * nt;
            int ri1 = sIdx[ti1 * 16 + mrow], rj1 = sIdx[tj1 * 16 + mrow];
            int ri2 = sIdx[ti2 * 16 + mrow], rj2 = sIdx[tj2 * 16 + mrow];

            const u8* pa1 = A + (size_t)ri1 * DIM + q * 32;
            const u8* pb1 = B + (size_t)rj1 * DIM + q * 32;
            const u8* pa2 = A + (size_t)ri2 * DIM + q * 32;
            const u8* pb2 = B + (size_t)rj2 * DIM + q * 32;

            i32x8 aF1, bF1, aF2, bF2;
            *((i32x4*)&aF1)     = *(const i32x4*)pa1;
            *((i32x4*)&aF1 + 1) = *(const i32x4*)(pa1 + 16);
            *((i32x4*)&bF1)     = *(const i32x4*)pb1;
            *((i32x4*)&bF1 + 1) = *(const i32x4*)(pb1 + 16);
            *((i32x4*)&aF2)     = *(const i32x4*)pa2;
            *((i32x4*)&aF2 + 1) = *(const i32x4*)(pa2 + 16);
            *((i32x4*)&bF2)     = *(const i32x4*)pb2;
            *((i32x4*)&bF2 + 1) = *(const i32x4*)(pb2 + 16);

            f32x4 acc1 = (f32x4){0.f, 0.f, 0.f, 0.f};
            f32x4 acc2 = (f32x4){0.f, 0.f, 0.f, 0.f};
            acc1 = __builtin_amdgcn_mfma_scale_f32_16x16x128_f8f6f4(
                aF1, bF1, acc1, 0, 0, 0, SCALE1, 0, SCALE1);
            acc2 = __builtin_amdgcn_mfma_scale_f32_16x16x128_f8f6f4(
                aF2, bF2, acc2, 0, 0, 0, SCALE1, 0, SCALE1);

            int i1 = ti1 * 16 + q * 4, j1 = tj1 * 16 + mrow;
            int i2 = ti2 * 16 + q * 4, j2 = tj2 * 16 + mrow;
            #pragma unroll
            for (int r = 0; r < 4; r++) {
                float e1 = __builtin_amdgcn_exp2f(acc1[r]);
                s += ((i1 + r) < k && j1 < k) ? e1 : 0.0f;
                float e2 = __builtin_amdgcn_exp2f(acc2[r]);
                s += (has2 && (i2 + r) < k && j2 < k) ? e2 : 0.0f;
            }
        }

        #pragma unroll
        for (int off = 32; off; off >>= 1) s += __shfl_xor(s, off, 64);
        if (lane == 0) red[w] = s;
        __syncthreads();
        if (tid == 0)
            atomicAdd(out, -(red[0] + red[1] + red[2] + red[3]) * SCALE);
        return;
    }

    // ---------------- maskless GEMM path ----------------
    int g  = blockIdx.x - NCORR;
    int wr = w >> 1;
    int wc = w & 1;

    int rowBase = (g >> 5) * 128;
    int colBase = (g & 31) * 512;

    // Staging pattern: LDS granule g of row m holds global granule g^(m&7).
    int m0 = tid >> 3;
    int p0 = tid & 7;
    int srcOff = m0 * 128 + ((p0 ^ (m0 & 7)) << 4);
    int ldsOff = (tid - lane) * 16;      // wave-uniform base

    const u8* gA = A + (size_t)rowBase * DIM + srcOff;
    const u8* gB = B + (size_t)colBase * DIM + srcOff;

    {
        const u8* gpA = gA;
        const u8* gpB = gB;
        u8* lpA = &sA[ldsOff];
        u8* lpB = &sB[0][ldsOff];
        #pragma unroll
        for (int it = 0; it < 4; it++) {
            __builtin_amdgcn_global_load_lds(
                (const __attribute__((address_space(1))) void*)gpA,
                (__attribute__((address_space(3))) void*)lpA, 16, 0, 0);
            __builtin_amdgcn_global_load_lds(
                (const __attribute__((address_space(1))) void*)gpB,
                (__attribute__((address_space(3))) void*)lpB, 16, 0, 0);
            gpA += 4096; gpB += 4096; lpA += 4096; lpB += 4096;
        }
    }

    // Fragment LDS byte offsets: low granule (2q)^(row&7); high = ^16.
    int aOff[4], bOff[4];
    #pragma unroll
    for (int mi = 0; mi < 4; mi++) {
        int m = wr * 64 + mi * 16 + mrow;
        aOff[mi] = m * 128 + (((q << 1) ^ (m & 7)) << 4);
        int n = wc * 64 + mi * 16 + mrow;
        bOff[mi] = n * 128 + (((q << 1) ^ (n & 7)) << 4);
    }

    __syncthreads();   // A + B0 resident

    // A operands register-resident for all 4 tiles (32 VGPRs).
    i32x8 a8[4];
    #pragma unroll
    for (int mi = 0; mi < 4; mi++) {
        *((i32x4*)&a8[mi])     = *(const i32x4*)(sA + aOff[mi]);
        *((i32x4*)&a8[mi] + 1) = *(const i32x4*)(sA + (aOff[mi] ^ 16));
    }

    float s = 0.0f;

    #pragma unroll
    for (int jt = 0; jt < 4; jt++) {
        if (jt < 3) {
            const u8* gp = gB + (jt + 1) * (128 * DIM);
            u8* lp = &sB[(jt + 1) & 1][ldsOff];
            #pragma unroll
            for (int it = 0; it < 4; it++) {
                __builtin_amdgcn_global_load_lds(
                    (const __attribute__((address_space(1))) void*)gp,
                    (__attribute__((address_space(3))) void*)lp, 16, 0, 0);
                gp += 4096; lp += 4096;
            }
        }

        const u8* sb = sB[jt & 1];
        i32x8 b8[4];
        #pragma unroll
        for (int ni = 0; ni < 4; ni++) {
            *((i32x4*)&b8[ni])     = *(const i32x4*)(sb + bOff[ni]);
            *((i32x4*)&b8[ni] + 1) = *(const i32x4*)(sb + (bOff[ni] ^ 16));
        }

        f32x4 acc[4][4];
        #pragma unroll
        for (int mi = 0; mi < 4; mi++)
            #pragma unroll
            for (int ni = 0; ni < 4; ni++)
                acc[mi][ni] = (f32x4){0.f, 0.f, 0.f, 0.f};

        #pragma unroll
        for (int mi = 0; mi < 4; mi++)
            #pragma unroll
            for (int ni = 0; ni < 4; ni++)
                acc[mi][ni] = __builtin_amdgcn_mfma_scale_f32_16x16x128_f8f6f4(
                    a8[mi], b8[ni], acc[mi][ni], 0, 0, 0, SCALE1, 0, SCALE1);

        // Maskless epilogue: exp2 + add only.
        float s0 = 0.0f, s1 = 0.0f;
        #pragma unroll
        for (int mi = 0; mi < 4; mi++)
            #pragma unroll
            for (int ni = 0; ni < 4; ni++)
                #pragma unroll
                for (int r = 0; r < 4; r++) {
                    float e = __builtin_amdgcn_exp2f(acc[mi][ni][r]);
                    if (r & 1) s1 += e; else s0 += e;
                }
        s += s0 + s1;

        __syncthreads();
    }

    #pragma unroll
    for (int off = 32; off; off >>= 1) s += __shfl_xor(s, off, 64);

    __shared__ float red[4];
    if (lane == 0) red[w] = s;
    __syncthreads();
    if (tid == 0) {
        float t = (red[0] + red[1]) + (red[2] + red[3]);
        atomicAdd(out, t * SCALE);
    }
}

extern "C" void kernel_launch(void* const* d_in, const int* in_sizes, int n_in,
                              void* d_out, int out_size, void* d_ws, size_t ws_size,
                              hipStream_t stream) {
    const float* self_p = (const float*)d_in[0];
    const float* pos_p  = (const float*)d_in[1];
    const int*   labels = (const int*)d_in[2];
    float* out = (float*)d_out;

    u8* aB = (u8*)d_ws;                         // 2 MB fp8 normalized self
    u8* bB = aB + (size_t)NROWS * DIM;          // 2 MB fp8 normalized pos (pre-scaled)

    norm_kernel<<<NROWS / 8, 256, 0, stream>>>(self_p, pos_p, aB, bB, out);
    gemm_kernel<<<NCORR + NGEMM, 256, 0, stream>>>(aB, bB, labels, out);
}

// Round 9
// 114.097 us; speedup vs baseline: 1.6447x; 1.1160x over previous
//
#include <hip/hip_runtime.h>

typedef unsigned char u8;
typedef unsigned short u16;
typedef float f32x4 __attribute__((ext_vector_type(4)));
typedef int i32x4 __attribute__((ext_vector_type(4)));
typedef int i32x8 __attribute__((ext_vector_type(8)));

#define NROWS 16384
#define DIM 128

// exp(-2*sim) = exp2(sim * -2*log2(e)); scale folded into normalized B rows.
#define NEG2LOG2E -2.8853900817779268f
#define SCALE ((float)(1.0 / (16384.0 * 16383.0)))

// E8M0 scale byte 127 = 2^0 = 1.0, replicated.
#define SCALE1 0x7F7F7F7F

#define KMAX 320
#define NCORR 100
#define NGEMM 4096

// Two rows per wave (half-wave per row): float4 loads, half-wave shuffle
// reduction, paired cvt_pk_fp8 -> one dword store per lane (fully coalesced).
// B rows pre-scaled by -2*log2(e) so GEMM output feeds exp2 directly.
__global__ __launch_bounds__(256) void norm_kernel(
    const float* __restrict__ a, const float* __restrict__ b,
    u8* __restrict__ aO, u8* __restrict__ bO)
{
    int tid  = threadIdx.x;
    int lane = tid & 63;
    int w    = tid >> 6;
    int half = lane >> 5;
    int l32  = lane & 31;
    long row = (long)blockIdx.x * 8 + w * 2 + half;

    const float4 va = ((const float4*)(a + row * DIM))[l32];
    float sa = va.x * va.x + va.y * va.y + va.z * va.z + va.w * va.w;
    #pragma unroll
    for (int off = 16; off; off >>= 1) sa += __shfl_xor(sa, off, 64);
    float inva = 1.0f / fmaxf(sqrtf(sa), 1e-12f);
    int pa = __builtin_amdgcn_cvt_pk_fp8_f32(va.x * inva, va.y * inva, 0, false);
    pa = __builtin_amdgcn_cvt_pk_fp8_f32(va.z * inva, va.w * inva, pa, true);
    ((int*)(aO + row * DIM))[l32] = pa;

    const float4 vb = ((const float4*)(b + row * DIM))[l32];
    float sb = vb.x * vb.x + vb.y * vb.y + vb.z * vb.z + vb.w * vb.w;
    #pragma unroll
    for (int off = 16; off; off >>= 1) sb += __shfl_xor(sb, off, 64);
    float invb = NEG2LOG2E / fmaxf(sqrtf(sb), 1e-12f);
    int pb = __builtin_amdgcn_cvt_pk_fp8_f32(vb.x * invb, vb.y * invb, 0, false);
    pb = __builtin_amdgcn_cvt_pk_fp8_f32(vb.z * invb, vb.w * invb, pb, true);
    ((int*)(bO + row * DIM))[l32] = pb;
}

// 1D grid of 100 + 4096 blocks. IDs 0..99: correction block for label id —
// dispatched FIRST so their latency chains hide under the gemm fill phase
// and their L2 pollution is confined to warm-up. IDs 100+: maskless 128x512
// GEMM strip (sums exp over ALL pairs); same-label sums subtracted exactly
// in reduce.
//
// R19 (= R18 resubmit after infra flake): exact R0/session-best
// configuration (112.7/114.4 us, reproduced twice). Session ledger:
// occupancy-squeeze (R11), LDS-free (R12), barrier-free private staging
// (R14), SGB in-wave pipeline (R15), fence-fused reduce (R16,
// catastrophic: per-block __threadfence forces L2 writebacks on
// non-coherent XCDs), atomic-fused reduce (R17) -- ALL regressed or
// tied-within-noise; busy-cycles (MFMA ~13us, VALU ~27us) are
// structure-invariant, and harness overhead (~54us) is launch-count-
// independent. This structure is the measured argmin.
__global__ __launch_bounds__(256, 3) void gemm_kernel(
    const u8* __restrict__ A, const u8* __restrict__ B,
    const int* __restrict__ labels,
    float* __restrict__ partials, float* __restrict__ corrP)
{
    __shared__ u8 sA[16384];
    __shared__ u8 sB[2][16384];

    int tid  = threadIdx.x;
    int lane = tid & 63;
    int w    = tid >> 6;
    int mrow = lane & 15;
    int q    = lane >> 4;

    if (blockIdx.x < NCORR) {
        // ---------------- correction path (early blocks) ----------------
        int l = blockIdx.x;
        int* sIdx = (int*)sA;                 // KMAX ints
        __shared__ int sCnt;
        __shared__ float red[4];
        if (tid == 0) sCnt = 0;
        __syncthreads();

        for (int i = tid; i < NROWS; i += 256)
            if (labels[i] == l) {
                int p = atomicAdd(&sCnt, 1);
                if (p < KMAX) sIdx[p] = i;
            }
        __syncthreads();

        int k = sCnt < KMAX ? sCnt : KMAX;
        int nt = (k + 15) >> 4;
        int ntk = nt << 4;
        for (int r = k + tid; r < ntk; r += 256) sIdx[r] = sIdx[0];  // pad
        __syncthreads();

        int npairs = nt * nt;
        float s = 0.0f;
        // 2-deep software pipeline: two tile-pairs per iteration, gathers
        // issued together so their L2 latency overlaps.
        for (int tp = w; tp < npairs; tp += 8) {
            int tpB = tp + 4;
            bool has2 = tpB < npairs;
            int tp2 = has2 ? tpB : tp;

            int ti1 = tp / nt,  tj1 = tp  - ti1 * nt;
            int ti2 = tp2 / nt, tj2 = tp2 - ti2 * nt;
            int ri1 = sIdx[ti1 * 16 + mrow], rj1 = sIdx[tj1 * 16 + mrow];
            int ri2 = sIdx[ti2 * 16 + mrow], rj2 = sIdx[tj2 * 16 + mrow];

            const u8* pa1 = A + (size_t)ri1 * DIM + q * 32;
            const u8* pb1 = B + (size_t)rj1 * DIM + q * 32;
            const u8* pa2 = A + (size_t)ri2 * DIM + q * 32;
            const u8* pb2 = B + (size_t)rj2 * DIM + q * 32;

            i32x8 aF1, bF1, aF2, bF2;
            *((i32x4*)&aF1)     = *(const i32x4*)pa1;
            *((i32x4*)&aF1 + 1) = *(const i32x4*)(pa1 + 16);
            *((i32x4*)&bF1)     = *(const i32x4*)pb1;
            *((i32x4*)&bF1 + 1) = *(const i32x4*)(pb1 + 16);
            *((i32x4*)&aF2)     = *(const i32x4*)pa2;
            *((i32x4*)&aF2 + 1) = *(const i32x4*)(pa2 + 16);
            *((i32x4*)&bF2)     = *(const i32x4*)pb2;
            *((i32x4*)&bF2 + 1) = *(const i32x4*)(pb2 + 16);

            f32x4 acc1 = (f32x4){0.f, 0.f, 0.f, 0.f};
            f32x4 acc2 = (f32x4){0.f, 0.f, 0.f, 0.f};
            acc1 = __builtin_amdgcn_mfma_scale_f32_16x16x128_f8f6f4(
                aF1, bF1, acc1, 0, 0, 0, SCALE1, 0, SCALE1);
            acc2 = __builtin_amdgcn_mfma_scale_f32_16x16x128_f8f6f4(
                aF2, bF2, acc2, 0, 0, 0, SCALE1, 0, SCALE1);

            int i1 = ti1 * 16 + q * 4, j1 = tj1 * 16 + mrow;
            int i2 = ti2 * 16 + q * 4, j2 = tj2 * 16 + mrow;
            #pragma unroll
            for (int r = 0; r < 4; r++) {
                float e1 = __builtin_amdgcn_exp2f(acc1[r]);
                s += ((i1 + r) < k && j1 < k) ? e1 : 0.0f;
                float e2 = __builtin_amdgcn_exp2f(acc2[r]);
                s += (has2 && (i2 + r) < k && j2 < k) ? e2 : 0.0f;
            }
        }

        #pragma unroll
        for (int off = 32; off; off >>= 1) s += __shfl_xor(s, off, 64);
        if (lane == 0) red[w] = s;
        __syncthreads();
        if (tid == 0)
            corrP[l] = (red[0] + red[1] + red[2] + red[3]) * SCALE;
        return;
    }

    // ---------------- maskless GEMM path ----------------
    int g  = blockIdx.x - NCORR;
    int wr = w >> 1;
    int wc = w & 1;

    int rowBase = (g >> 5) * 128;
    int colBase = (g & 31) * 512;

    // Staging pattern: LDS granule g of row m holds global granule g^(m&7).
    int m0 = tid >> 3;
    int p0 = tid & 7;
    int srcOff = m0 * 128 + ((p0 ^ (m0 & 7)) << 4);
    int ldsOff = (tid - lane) * 16;      // wave-uniform base

    const u8* gA = A + (size_t)rowBase * DIM + srcOff;
    const u8* gB = B + (size_t)colBase * DIM + srcOff;

    {
        const u8* gpA = gA;
        const u8* gpB = gB;
        u8* lpA = &sA[ldsOff];
        u8* lpB = &sB[0][ldsOff];
        #pragma unroll
        for (int it = 0; it < 4; it++) {
            __builtin_amdgcn_global_load_lds(
                (const __attribute__((address_space(1))) void*)gpA,
                (__attribute__((address_space(3))) void*)lpA, 16, 0, 0);
            __builtin_amdgcn_global_load_lds(
                (const __attribute__((address_space(1))) void*)gpB,
                (__attribute__((address_space(3))) void*)lpB, 16, 0, 0);
            gpA += 4096; gpB += 4096; lpA += 4096; lpB += 4096;
        }
    }

    // Fragment LDS byte offsets: low granule (2q)^(row&7); high = ^16.
    int aOff[4], bOff[4];
    #pragma unroll
    for (int mi = 0; mi < 4; mi++) {
        int m = wr * 64 + mi * 16 + mrow;
        aOff[mi] = m * 128 + (((q << 1) ^ (m & 7)) << 4);
        int n = wc * 64 + mi * 16 + mrow;
        bOff[mi] = n * 128 + (((q << 1) ^ (n & 7)) << 4);
    }

    __syncthreads();   // A + B0 resident

    // A operands register-resident for all 4 tiles (32 VGPRs).
    i32x8 a8[4];
    #pragma unroll
    for (int mi = 0; mi < 4; mi++) {
        *((i32x4*)&a8[mi])     = *(const i32x4*)(sA + aOff[mi]);
        *((i32x4*)&a8[mi] + 1) = *(const i32x4*)(sA + (aOff[mi] ^ 16));
    }

    float s = 0.0f;

    #pragma unroll
    for (int jt = 0; jt < 4; jt++) {
        if (jt < 3) {
            const u8* gp = gB + (jt + 1) * (128 * DIM);
            u8* lp = &sB[(jt + 1) & 1][ldsOff];
            #pragma unroll
            for (int it = 0; it < 4; it++) {
                __builtin_amdgcn_global_load_lds(
                    (const __attribute__((address_space(1))) void*)gp,
                    (__attribute__((address_space(3))) void*)lp, 16, 0, 0);
                gp += 4096; lp += 4096;
            }
        }

        const u8* sb = sB[jt & 1];
        i32x8 b8[4];
        #pragma unroll
        for (int ni = 0; ni < 4; ni++) {
            *((i32x4*)&b8[ni])     = *(const i32x4*)(sb + bOff[ni]);
            *((i32x4*)&b8[ni] + 1) = *(const i32x4*)(sb + (bOff[ni] ^ 16));
        }

        f32x4 acc[4][4];
        #pragma unroll
        for (int mi = 0; mi < 4; mi++)
            #pragma unroll
            for (int ni = 0; ni < 4; ni++)
                acc[mi][ni] = (f32x4){0.f, 0.f, 0.f, 0.f};

        #pragma unroll
        for (int mi = 0; mi < 4; mi++)
            #pragma unroll
            for (int ni = 0; ni < 4; ni++)
                acc[mi][ni] = __builtin_amdgcn_mfma_scale_f32_16x16x128_f8f6f4(
                    a8[mi], b8[ni], acc[mi][ni], 0, 0, 0, SCALE1, 0, SCALE1);

        // Maskless epilogue: exp2 + add only.
        float s0 = 0.0f, s1 = 0.0f;
        #pragma unroll
        for (int mi = 0; mi < 4; mi++)
            #pragma unroll
            for (int ni = 0; ni < 4; ni++)
                #pragma unroll
                for (int r = 0; r < 4; r++) {
                    float e = __builtin_amdgcn_exp2f(acc[mi][ni][r]);
                    if (r & 1) s1 += e; else s0 += e;
                }
        s += s0 + s1;

        __syncthreads();
    }

    #pragma unroll
    for (int off = 32; off; off >>= 1) s += __shfl_xor(s, off, 64);

    float* red = (float*)sA;
    if (lane == 0) red[w] = s;
    __syncthreads();
    if (tid == 0) {
        float t = (red[0] + red[1]) + (red[2] + red[3]);
        partials[g] = t * SCALE;
    }
}

__global__ __launch_bounds__(256) void reduce_kernel(
    const float* __restrict__ gP, const float* __restrict__ cP,
    float* __restrict__ out)
{
    int tid = threadIdx.x;
    const float4* p4 = (const float4*)gP;
    float s = 0.0f;
    #pragma unroll 4
    for (int i = tid; i < 1024; i += 256) {
        float4 v = p4[i];
        s += (v.x + v.y) + (v.z + v.w);
    }
    if (tid < NCORR) s -= cP[tid];
    #pragma unroll
    for (int off = 32; off; off >>= 1) s += __shfl_xor(s, off, 64);
    __shared__ float red[4];
    if ((tid & 63) == 0) red[tid >> 6] = s;
    __syncthreads();
    if (tid == 0) out[0] = (red[0] + red[1]) + (red[2] + red[3]);
}

extern "C" void kernel_launch(void* const* d_in, const int* in_sizes, int n_in,
                              void* d_out, int out_size, void* d_ws, size_t ws_size,
                              hipStream_t stream) {
    const float* self_p = (const float*)d_in[0];
    const float* pos_p  = (const float*)d_in[1];
    const int*   labels = (const int*)d_in[2];
    float* out = (float*)d_out;

    u8* aB = (u8*)d_ws;                         // 2 MB fp8 normalized self
    u8* bB = aB + (size_t)NROWS * DIM;          // 2 MB fp8 normalized pos (pre-scaled)
    float* gemmP = (float*)(bB + (size_t)NROWS * DIM);     // 16 KB
    float* corrP = gemmP + NGEMM;                           // 400 B (100 used)

    norm_kernel<<<NROWS / 8, 256, 0, stream>>>(self_p, pos_p, aB, bB);
    gemm_kernel<<<NCORR + NGEMM, 256, 0, stream>>>(aB, bB, labels, gemmP, corrP);
    reduce_kernel<<<1, 256, 0, stream>>>(gemmP, corrP, out);
}

// Round 10
// 111.049 us; speedup vs baseline: 1.6898x; 1.0274x over previous
//
#include <hip/hip_runtime.h>

typedef unsigned char u8;
typedef unsigned short u16;
typedef float f32x2 __attribute__((ext_vector_type(2)));
typedef float f32x4 __attribute__((ext_vector_type(4)));
typedef int i32x4 __attribute__((ext_vector_type(4)));
typedef int i32x8 __attribute__((ext_vector_type(8)));

#define NROWS 16384
#define DIM 128

// exp(-2*sim) = exp2(sim * -2*log2(e)); scale folded into normalized B rows.
#define NEG2LOG2E -2.8853900817779268f
#define SCALE ((float)(1.0 / (16384.0 * 16383.0)))

// E8M0 scale byte 127 = 2^0 = 1.0, replicated.
#define SCALE1 0x7F7F7F7F

#define KMAX 320
#define NCORR 100
#define NGEMM 4096

// Two rows per wave (half-wave per row): float4 loads, half-wave shuffle
// reduction, paired cvt_pk_fp8 -> one dword store per lane (fully coalesced).
// B rows pre-scaled by -2*log2(e) so GEMM output feeds exp2 directly.
__global__ __launch_bounds__(256) void norm_kernel(
    const float* __restrict__ a, const float* __restrict__ b,
    u8* __restrict__ aO, u8* __restrict__ bO)
{
    int tid  = threadIdx.x;
    int lane = tid & 63;
    int w    = tid >> 6;
    int half = lane >> 5;
    int l32  = lane & 31;
    long row = (long)blockIdx.x * 8 + w * 2 + half;

    const float4 va = ((const float4*)(a + row * DIM))[l32];
    float sa = va.x * va.x + va.y * va.y + va.z * va.z + va.w * va.w;
    #pragma unroll
    for (int off = 16; off; off >>= 1) sa += __shfl_xor(sa, off, 64);
    float inva = 1.0f / fmaxf(sqrtf(sa), 1e-12f);
    int pa = __builtin_amdgcn_cvt_pk_fp8_f32(va.x * inva, va.y * inva, 0, false);
    pa = __builtin_amdgcn_cvt_pk_fp8_f32(va.z * inva, va.w * inva, pa, true);
    ((int*)(aO + row * DIM))[l32] = pa;

    const float4 vb = ((const float4*)(b + row * DIM))[l32];
    float sb = vb.x * vb.x + vb.y * vb.y + vb.z * vb.z + vb.w * vb.w;
    #pragma unroll
    for (int off = 16; off; off >>= 1) sb += __shfl_xor(sb, off, 64);
    float invb = NEG2LOG2E / fmaxf(sqrtf(sb), 1e-12f);
    int pb = __builtin_amdgcn_cvt_pk_fp8_f32(vb.x * invb, vb.y * invb, 0, false);
    pb = __builtin_amdgcn_cvt_pk_fp8_f32(vb.z * invb, vb.w * invb, pb, true);
    ((int*)(bO + row * DIM))[l32] = pb;
}

// 1D grid of 100 + 4096 blocks. IDs 0..99: correction block for label id —
// dispatched FIRST so their latency chains hide under the gemm fill phase
// and their L2 pollution is confined to warm-up. IDs 100+: maskless 128x512
// GEMM strip (sums exp over ALL pairs); same-label sums subtracted exactly
// in reduce.
//
// R20: exact R0/session-best structure (114.1us reproduced in R19), with
// ONE change: the maskless epilogue accumulates into float2 vectors so the
// 268M accumulate-adds lower to v_pk_add_f32 (packed 2xfp32, gfx90a+).
// VALU decomposition per CU: ~13.6us exp2 (unpackable, no packed trans)
// + ~13.6us scalar adds -> pk_add halves the add component. This targets
// the largest busy pipe (VALUBusy 52.5% = 27.2us of 51.8) instead of the
// stall, which six structural variants (R11-R17) proved invariant.
__global__ __launch_bounds__(256, 3) void gemm_kernel(
    const u8* __restrict__ A, const u8* __restrict__ B,
    const int* __restrict__ labels,
    float* __restrict__ partials, float* __restrict__ corrP)
{
    __shared__ u8 sA[16384];
    __shared__ u8 sB[2][16384];

    int tid  = threadIdx.x;
    int lane = tid & 63;
    int w    = tid >> 6;
    int mrow = lane & 15;
    int q    = lane >> 4;

    if (blockIdx.x < NCORR) {
        // ---------------- correction path (early blocks) ----------------
        int l = blockIdx.x;
        int* sIdx = (int*)sA;                 // KMAX ints
        __shared__ int sCnt;
        __shared__ float red[4];
        if (tid == 0) sCnt = 0;
        __syncthreads();

        for (int i = tid; i < NROWS; i += 256)
            if (labels[i] == l) {
                int p = atomicAdd(&sCnt, 1);
                if (p < KMAX) sIdx[p] = i;
            }
        __syncthreads();

        int k = sCnt < KMAX ? sCnt : KMAX;
        int nt = (k + 15) >> 4;
        int ntk = nt << 4;
        for (int r = k + tid; r < ntk; r += 256) sIdx[r] = sIdx[0];  // pad
        __syncthreads();

        int npairs = nt * nt;
        float s = 0.0f;
        // 2-deep software pipeline: two tile-pairs per iteration, gathers
        // issued together so their L2 latency overlaps.
        for (int tp = w; tp < npairs; tp += 8) {
            int tpB = tp + 4;
            bool has2 = tpB < npairs;
            int tp2 = has2 ? tpB : tp;

            int ti1 = tp / nt,  tj1 = tp  - ti1 * nt;
            int ti2 = tp2 / nt, tj2 = tp2 - ti2 * nt;
            int ri1 = sIdx[ti1 * 16 + mrow], rj1 = sIdx[tj1 * 16 + mrow];
            int ri2 = sIdx[ti2 * 16 + mrow], rj2 = sIdx[tj2 * 16 + mrow];

            const u8* pa1 = A + (size_t)ri1 * DIM + q * 32;
            const u8* pb1 = B + (size_t)rj1 * DIM + q * 32;
            const u8* pa2 = A + (size_t)ri2 * DIM + q * 32;
            const u8* pb2 = B + (size_t)rj2 * DIM + q * 32;

            i32x8 aF1, bF1, aF2, bF2;
            *((i32x4*)&aF1)     = *(const i32x4*)pa1;
            *((i32x4*)&aF1 + 1) = *(const i32x4*)(pa1 + 16);
            *((i32x4*)&bF1)     = *(const i32x4*)pb1;
            *((i32x4*)&bF1 + 1) = *(const i32x4*)(pb1 + 16);
            *((i32x4*)&aF2)     = *(const i32x4*)pa2;
            *((i32x4*)&aF2 + 1) = *(const i32x4*)(pa2 + 16);
            *((i32x4*)&bF2)     = *(const i32x4*)pb2;
            *((i32x4*)&bF2 + 1) = *(const i32x4*)(pb2 + 16);

            f32x4 acc1 = (f32x4){0.f, 0.f, 0.f, 0.f};
            f32x4 acc2 = (f32x4){0.f, 0.f, 0.f, 0.f};
            acc1 = __builtin_amdgcn_mfma_scale_f32_16x16x128_f8f6f4(
                aF1, bF1, acc1, 0, 0, 0, SCALE1, 0, SCALE1);
            acc2 = __builtin_amdgcn_mfma_scale_f32_16x16x128_f8f6f4(
                aF2, bF2, acc2, 0, 0, 0, SCALE1, 0, SCALE1);

            int i1 = ti1 * 16 + q * 4, j1 = tj1 * 16 + mrow;
            int i2 = ti2 * 16 + q * 4, j2 = tj2 * 16 + mrow;
            #pragma unroll
            for (int r = 0; r < 4; r++) {
                float e1 = __builtin_amdgcn_exp2f(acc1[r]);
                s += ((i1 + r) < k && j1 < k) ? e1 : 0.0f;
                float e2 = __builtin_amdgcn_exp2f(acc2[r]);
                s += (has2 && (i2 + r) < k && j2 < k) ? e2 : 0.0f;
            }
        }

        #pragma unroll
        for (int off = 32; off; off >>= 1) s += __shfl_xor(s, off, 64);
        if (lane == 0) red[w] = s;
        __syncthreads();
        if (tid == 0)
            corrP[l] = (red[0] + red[1] + red[2] + red[3]) * SCALE;
        return;
    }

    // ---------------- maskless GEMM path ----------------
    int g  = blockIdx.x - NCORR;
    int wr = w >> 1;
    int wc = w & 1;

    int rowBase = (g >> 5) * 128;
    int colBase = (g & 31) * 512;

    // Staging pattern: LDS granule g of row m holds global granule g^(m&7).
    int m0 = tid >> 3;
    int p0 = tid & 7;
    int srcOff = m0 * 128 + ((p0 ^ (m0 & 7)) << 4);
    int ldsOff = (tid - lane) * 16;      // wave-uniform base

    const u8* gA = A + (size_t)rowBase * DIM + srcOff;
    const u8* gB = B + (size_t)colBase * DIM + srcOff;

    {
        const u8* gpA = gA;
        const u8* gpB = gB;
        u8* lpA = &sA[ldsOff];
        u8* lpB = &sB[0][ldsOff];
        #pragma unroll
        for (int it = 0; it < 4; it++) {
            __builtin_amdgcn_global_load_lds(
                (const __attribute__((address_space(1))) void*)gpA,
                (__attribute__((address_space(3))) void*)lpA, 16, 0, 0);
            __builtin_amdgcn_global_load_lds(
                (const __attribute__((address_space(1))) void*)gpB,
                (__attribute__((address_space(3))) void*)lpB, 16, 0, 0);
            gpA += 4096; gpB += 4096; lpA += 4096; lpB += 4096;
        }
    }

    // Fragment LDS byte offsets: low granule (2q)^(row&7); high = ^16.
    int aOff[4], bOff[4];
    #pragma unroll
    for (int mi = 0; mi < 4; mi++) {
        int m = wr * 64 + mi * 16 + mrow;
        aOff[mi] = m * 128 + (((q << 1) ^ (m & 7)) << 4);
        int n = wc * 64 + mi * 16 + mrow;
        bOff[mi] = n * 128 + (((q << 1) ^ (n & 7)) << 4);
    }

    __syncthreads();   // A + B0 resident

    // A operands register-resident for all 4 tiles (32 VGPRs).
    i32x8 a8[4];
    #pragma unroll
    for (int mi = 0; mi < 4; mi++) {
        *((i32x4*)&a8[mi])     = *(const i32x4*)(sA + aOff[mi]);
        *((i32x4*)&a8[mi] + 1) = *(const i32x4*)(sA + (aOff[mi] ^ 16));
    }

    // Packed accumulators: float2 fadd lowers to v_pk_add_f32 (one inst
    // per two accumulates) -- halves the 268M add component of the VALU.
    f32x2 S01 = (f32x2){0.f, 0.f};
    f32x2 S23 = (f32x2){0.f, 0.f};

    #pragma unroll
    for (int jt = 0; jt < 4; jt++) {
        if (jt < 3) {
            const u8* gp = gB + (jt + 1) * (128 * DIM);
            u8* lp = &sB[(jt + 1) & 1][ldsOff];
            #pragma unroll
            for (int it = 0; it < 4; it++) {
                __builtin_amdgcn_global_load_lds(
                    (const __attribute__((address_space(1))) void*)gp,
                    (__attribute__((address_space(3))) void*)lp, 16, 0, 0);
                gp += 4096; lp += 4096;
            }
        }

        const u8* sb = sB[jt & 1];
        i32x8 b8[4];
        #pragma unroll
        for (int ni = 0; ni < 4; ni++) {
            *((i32x4*)&b8[ni])     = *(const i32x4*)(sb + bOff[ni]);
            *((i32x4*)&b8[ni] + 1) = *(const i32x4*)(sb + (bOff[ni] ^ 16));
        }

        f32x4 acc[4][4];
        #pragma unroll
        for (int mi = 0; mi < 4; mi++)
            #pragma unroll
            for (int ni = 0; ni < 4; ni++)
                acc[mi][ni] = (f32x4){0.f, 0.f, 0.f, 0.f};

        #pragma unroll
        for (int mi = 0; mi < 4; mi++)
            #pragma unroll
            for (int ni = 0; ni < 4; ni++)
                acc[mi][ni] = __builtin_amdgcn_mfma_scale_f32_16x16x128_f8f6f4(
                    a8[mi], b8[ni], acc[mi][ni], 0, 0, 0, SCALE1, 0, SCALE1);

        // Maskless epilogue: exp2 then packed accumulate (v_pk_add_f32).
        #pragma unroll
        for (int mi = 0; mi < 4; mi++)
            #pragma unroll
            for (int ni = 0; ni < 4; ni++) {
                f32x2 e01, e23;
                e01.x = __builtin_amdgcn_exp2f(acc[mi][ni][0]);
                e01.y = __builtin_amdgcn_exp2f(acc[mi][ni][1]);
                e23.x = __builtin_amdgcn_exp2f(acc[mi][ni][2]);
                e23.y = __builtin_amdgcn_exp2f(acc[mi][ni][3]);
                S01 += e01;
                S23 += e23;
            }

        __syncthreads();
    }

    float s = (S01.x + S23.x) + (S01.y + S23.y);
    #pragma unroll
    for (int off = 32; off; off >>= 1) s += __shfl_xor(s, off, 64);

    float* red = (float*)sA;
    if (lane == 0) red[w] = s;
    __syncthreads();
    if (tid == 0) {
        float t = (red[0] + red[1]) + (red[2] + red[3]);
        partials[g] = t * SCALE;
    }
}

__global__ __launch_bounds__(256) void reduce_kernel(
    const float* __restrict__ gP, const float* __restrict__ cP,
    float* __restrict__ out)
{
    int tid = threadIdx.x;
    const float4* p4 = (const float4*)gP;
    float s = 0.0f;
    #pragma unroll 4
    for (int i = tid; i < 1024; i += 256) {
        float4 v = p4[i];
        s += (v.x + v.y) + (v.z + v.w);
    }
    if (tid < NCORR) s -= cP[tid];
    #pragma unroll
    for (int off = 32; off; off >>= 1) s += __shfl_xor(s, off, 64);
    __shared__ float red[4];
    if ((tid & 63) == 0) red[tid >> 6] = s;
    __syncthreads();
    if (tid == 0) out[0] = (red[0] + red[1]) + (red[2] + red[3]);
}

extern "C" void kernel_launch(void* const* d_in, const int* in_sizes, int n_in,
                              void* d_out, int out_size, void* d_ws, size_t ws_size,
                              hipStream_t stream) {
    const float* self_p = (const float*)d_in[0];
    const float* pos_p  = (const float*)d_in[1];
    const int*   labels = (const int*)d_in[2];
    float* out = (float*)d_out;

    u8* aB = (u8*)d_ws;                         // 2 MB fp8 normalized self
    u8* bB = aB + (size_t)NROWS * DIM;          // 2 MB fp8 normalized pos (pre-scaled)
    float* gemmP = (float*)(bB + (size_t)NROWS * DIM);     // 16 KB
    float* corrP = gemmP + NGEMM;                           // 400 B (100 used)

    norm_kernel<<<NROWS / 8, 256, 0, stream>>>(self_p, pos_p, aB, bB);
    gemm_kernel<<<NCORR + NGEMM, 256, 0, stream>>>(aB, bB, labels, gemmP, corrP);
    reduce_kernel<<<1, 256, 0, stream>>>(gemmP, corrP, out);
}